// Round 12
// baseline (592.815 us; speedup 1.0000x reference)
//
#include <hip/hip_runtime.h>

#define TB 262144

typedef short bf16x8 __attribute__((ext_vector_type(8)));
typedef float f32x4v __attribute__((ext_vector_type(4)));
typedef unsigned short u16x4 __attribute__((ext_vector_type(4)));

__device__ __forceinline__ unsigned short f2bf(float f) {
  unsigned int u = __float_as_uint(f);
  unsigned int r = (u + 0x7fffu + ((u >> 16) & 1u)) >> 16;
  return (unsigned short)r;
}
__device__ __forceinline__ float bf2f(unsigned short u) {
  return __uint_as_float(((unsigned int)u) << 16);
}
__device__ __forceinline__ float sigmoid_f(float x) {
  return __builtin_amdgcn_rcpf(1.f + __expf(-x));
}
__device__ __forceinline__ float tanh_f(float x) {
  return 1.f - 2.f * __builtin_amdgcn_rcpf(__expf(2.f * x) + 1.f);
}

// LDS-only barrier: wait for LDS ops, NOT global stores/loads.
#define LDS_BARRIER() asm volatile("s_waitcnt lgkmcnt(0)\n\ts_barrier" ::: "memory")

// Convert the 5 weight matrices to bf16 in workspace.
// Layout (ushort elems): [0,32768) w ; [32768,65536) wi ; [65536,98304) wf ;
//                        [98304,131072) wo ; [131072,147456) w_out
__global__ void wconv_kernel(const float* __restrict__ w, const float* __restrict__ wi,
                             const float* __restrict__ wf, const float* __restrict__ wo,
                             const float* __restrict__ wout, unsigned short* __restrict__ dst) {
  int i = blockIdx.x * 256 + threadIdx.x;
  float v;
  if (i < 32768) v = w[i];
  else if (i < 65536) v = wi[i - 32768];
  else if (i < 98304) v = wf[i - 65536];
  else if (i < 131072) v = wo[i - 98304];
  else v = wout[i - 131072];
  dst[i] = f2bf(v);
}

// Occupancy-first restructure: 512 threads (8 waves), 16 rows/block.
// Wave w computes ONE gate (w>>1) for one col-half (w&1) -> acc = 16 AGPR
// (was 64). Gates exchanged via LDS bf16; elementwise fully coalesced;
// GEMM2 in-block on waves 0-3. Target: 3 blocks/CU = 75% occupancy.
__global__ __launch_bounds__(512, 6) void lstm_main(
    const float* __restrict__ c_prev, const float* __restrict__ h_prev,
    const float* __restrict__ x, const unsigned short* __restrict__ wbf,
    const float* __restrict__ b, const float* __restrict__ bi,
    const float* __restrict__ bf_, const float* __restrict__ bo,
    const float* __restrict__ b_out,
    float* __restrict__ out_c, float* __restrict__ out_h, float* __restrict__ out_y) {
  // 29184 B total
  __shared__ unsigned short smem[14592];
  unsigned short* us_xh = smem;          // [16][256] bf16, XOR-swizzled (8 KB)
  unsigned short* gts   = smem + 4096;   // [4][16][132] bf16, padded (16.5 KB)
  unsigned short* us_h  = smem + 12544;  // [16][128] bf16, XOR-swizzled (4 KB)

  const int tid = threadIdx.x;   // 0..511
  const int wave = tid >> 6;
  const int lane = tid & 63;
  const int lr = lane & 15;
  const int lq = lane >> 4;      // 0..3
  const int row0 = blockIdx.x * 16;

  // ---- Phase 0: stage xh -> LDS. Waves 0-3 load x, waves 4-7 load h_. ----
  {
    const int t8 = tid & 255;
    const int r = t8 >> 4;           // 0..15
    const int k8 = (t8 & 15) * 8;    // 0..120
    const float* src = (tid < 256) ? &x[(size_t)(row0 + r) * 128 + k8]
                                   : &h_prev[(size_t)(row0 + r) * 128 + k8];
    const f32x4v v0 = __builtin_nontemporal_load(reinterpret_cast<const f32x4v*>(src));
    const f32x4v v1 = __builtin_nontemporal_load(reinterpret_cast<const f32x4v*>(src + 4));
    const int kb = k8 + ((tid < 256) ? 0 : 128);
    const int idx = (r * 256 + kb) ^ ((r & 7) << 3);
    u16x4 u0, u1;
    u0[0] = f2bf(v0[0]); u0[1] = f2bf(v0[1]); u0[2] = f2bf(v0[2]); u0[3] = f2bf(v0[3]);
    u1[0] = f2bf(v1[0]); u1[1] = f2bf(v1[1]); u1[2] = f2bf(v1[2]); u1[3] = f2bf(v1[3]);
    *reinterpret_cast<u16x4*>(&us_xh[idx]) = u0;
    *reinterpret_cast<u16x4*>(&us_xh[idx + 4]) = u1;
  }
  // Elementwise-phase mapping (also used for cpre issued early, T14):
  const int erow = tid >> 5;          // 0..15
  const int ec4 = (tid & 31) * 4;     // 0..124
  const f32x4v cpre = __builtin_nontemporal_load(
      reinterpret_cast<const f32x4v*>(&c_prev[(size_t)(row0 + erow) * 128 + ec4]));

  LDS_BARRIER();

  // ---- Phase 1: GEMM1 — this wave's gate x col-half, K=256 in 8 steps ----
  const int g = wave >> 1;
  const int colbase = (wave & 1) * 64;
  const unsigned short* wg = wbf + g * 32768;
  f32x4v acc[4] = {};
#pragma unroll
  for (int kk = 0; kk < 8; ++kk) {
    const int aidx = (lr * 256 + kk * 32 + lq * 8) ^ ((lr & 7) << 3);
    const bf16x8 a8 = *reinterpret_cast<const bf16x8*>(&us_xh[aidx]);
#pragma unroll
    for (int cf = 0; cf < 4; ++cf) {
      const int col = colbase + cf * 16 + lr;
      const bf16x8 wf8 =
          *reinterpret_cast<const bf16x8*>(&wg[col * 256 + kk * 32 + lq * 8]);
      acc[cf] = __builtin_amdgcn_mfma_f32_16x16x32_bf16(a8, wf8, acc[cf], 0, 0, 0);
    }
  }

  // ---- Phase 2: activation, gate -> LDS (bf16, padded rows: conflict-free) ----
  const float* bp = (g == 0) ? b : (g == 1) ? bi : (g == 2) ? bf_ : bo;
#pragma unroll
  for (int cf = 0; cf < 4; ++cf) {
    const int col = colbase + cf * 16 + lr;
    const float bias = bp[col];
#pragma unroll
    for (int ri = 0; ri < 4; ++ri) {
      const int rrow = lq * 4 + ri;
      float v = acc[cf][ri] + bias;
      v = (g == 0) ? tanh_f(v) : sigmoid_f(v);
      gts[g * 2112 + rrow * 132 + col] = f2bf(v);
    }
  }
  LDS_BARRIER();

  // ---- Phase 3: elementwise (fully coalesced), c/h stores, h -> LDS ----
  {
    const u16x4 uz = *reinterpret_cast<const u16x4*>(&gts[0 * 2112 + erow * 132 + ec4]);
    const u16x4 ui = *reinterpret_cast<const u16x4*>(&gts[1 * 2112 + erow * 132 + ec4]);
    const u16x4 uf = *reinterpret_cast<const u16x4*>(&gts[2 * 2112 + erow * 132 + ec4]);
    const u16x4 uo = *reinterpret_cast<const u16x4*>(&gts[3 * 2112 + erow * 132 + ec4]);
    f32x4v cv, hv;
    u16x4 hb;
#pragma unroll
    for (int j = 0; j < 4; ++j) {
      const float z  = bf2f(uz[j]);
      const float zi = bf2f(ui[j]);
      const float zf = bf2f(uf[j]);
      const float zo = bf2f(uo[j]);
      const float c = zf * cpre[j] + zi * z;
      const float h = zo * tanh_f(c);
      cv[j] = c;
      hv[j] = h;
      hb[j] = f2bf(h);
    }
    const size_t gi = (size_t)(row0 + erow) * 128 + ec4;
    __builtin_nontemporal_store(cv, reinterpret_cast<f32x4v*>(&out_c[gi]));
    __builtin_nontemporal_store(hv, reinterpret_cast<f32x4v*>(&out_h[gi]));
    *reinterpret_cast<u16x4*>(&us_h[(erow * 128 + ec4) ^ ((erow & 7) << 3)]) = hb;
  }
  LDS_BARRIER();

  // ---- Phase 4: GEMM2 (waves 0-3): y[16][32w..32w+32), K=128 in 4 steps ----
  if (wave < 4) {
    f32x4v acc2[2] = {};
#pragma unroll
    for (int ks = 0; ks < 4; ++ks) {
      const int aidx = (lr * 128 + ks * 32 + lq * 8) ^ ((lr & 7) << 3);
      const bf16x8 a8 = *reinterpret_cast<const bf16x8*>(&us_h[aidx]);
#pragma unroll
      for (int cf = 0; cf < 2; ++cf) {
        const int col = wave * 32 + cf * 16 + lr;
        const bf16x8 w2 =
            *reinterpret_cast<const bf16x8*>(&wbf[131072 + col * 128 + ks * 32 + lq * 8]);
        acc2[cf] = __builtin_amdgcn_mfma_f32_16x16x32_bf16(a8, w2, acc2[cf], 0, 0, 0);
      }
    }
#pragma unroll
    for (int ri = 0; ri < 4; ++ri) {
      const int rrow = lq * 4 + ri;
      const size_t gr = (size_t)(row0 + rrow) * 128;
      // Two adjacent 64B sectors of the same 128B line -> L2 write-combines.
      const int col0 = wave * 32 + lr;
      const int col1 = col0 + 16;
      __builtin_nontemporal_store(sigmoid_f(acc2[0][ri] + b_out[col0]), &out_y[gr + col0]);
      __builtin_nontemporal_store(sigmoid_f(acc2[1][ri] + b_out[col1]), &out_y[gr + col1]);
    }
  }
}

extern "C" void kernel_launch(void* const* d_in, const int* in_sizes, int n_in,
                              void* d_out, int out_size, void* d_ws, size_t ws_size,
                              hipStream_t stream) {
  const float* c_    = (const float*)d_in[0];
  const float* h_    = (const float*)d_in[1];
  const float* x     = (const float*)d_in[2];
  const float* w     = (const float*)d_in[3];
  const float* wi    = (const float*)d_in[4];
  const float* wf    = (const float*)d_in[5];
  const float* wo    = (const float*)d_in[6];
  const float* wout  = (const float*)d_in[7];
  const float* b     = (const float*)d_in[8];
  const float* bi    = (const float*)d_in[9];
  const float* bf_   = (const float*)d_in[10];
  const float* bo    = (const float*)d_in[11];
  const float* b_out = (const float*)d_in[12];

  unsigned short* wbf = (unsigned short*)d_ws;  // 147456 ushorts = 288 KiB
  float* out_c = (float*)d_out;
  float* out_h = out_c + (size_t)TB * 128;
  float* out_y = out_h + (size_t)TB * 128;

  hipLaunchKernelGGL(wconv_kernel, dim3(576), dim3(256), 0, stream,
                     w, wi, wf, wo, wout, wbf);
  hipLaunchKernelGGL(lstm_main, dim3(16384), dim3(512), 0, stream,
                     c_, h_, x, wbf, b, bi, bf_, bo, b_out, out_c, out_h, out_y);
}